// Round 8
// baseline (357.822 us; speedup 1.0000x reference)
//
#include <hip/hip_runtime.h>
#include <stdint.h>
#include <math.h>

typedef __attribute__((ext_vector_type(8))) short short8;
typedef __attribute__((ext_vector_type(4))) float f32x4;

#define S_LEN 2048
#define NBATCH 32
#define KDIM 1024
#define NEG_INF_F (-1e9f)

#define BM 256
#define BN 256

// round-half-up f32 -> bf16, two at a time, packed into one dword
__device__ __forceinline__ uint32_t pack_bf16(float f0, float f1) {
    union { float f; uint32_t u; } a, b; a.f = f0; b.f = f1;
    return ((a.u + 0x8000u) >> 16) | ((b.u + 0x8000u) & 0xFFFF0000u);
}

__device__ __forceinline__ void gload_lds16(const unsigned short* g, unsigned short* l) {
    __builtin_amdgcn_global_load_lds(
        (const __attribute__((address_space(1))) void*)g,
        (__attribute__((address_space(3))) void*)l, 16, 0, 0);
}

// tanh(x) = 1 - 2/(exp(2x)+1); __expf -> v_exp_f32, rcp -> v_rcp_f32 (~1e-7)
__device__ __forceinline__ float fast_tanh(float x) {
    float e = __expf(2.0f * x);
    return 1.0f - 2.0f * __builtin_amdgcn_rcpf(e + 1.0f);
}

// ---------------------------------------------------------------------------
// dec[b,e] = sum_d dh[b,d] * Ws[e,d]   (one block per e)
// ---------------------------------------------------------------------------
__global__ __launch_bounds__(256) void dec_kernel(
    const float* __restrict__ dh, const float* __restrict__ Ws,
    float* __restrict__ dec)
{
    __shared__ float wrow[1024];
    int e = blockIdx.x;
    int t = threadIdx.x;
    #pragma unroll
    for (int i = t; i < 1024; i += 256) wrow[i] = Ws[(size_t)e * 1024 + i];
    __syncthreads();
    int b = t >> 3, part = t & 7;
    const float* dhp = dh + (size_t)b * 1024 + part * 128;
    const float* wp  = wrow + part * 128;
    float s = 0.f;
    #pragma unroll 8
    for (int i = 0; i < 128; ++i) s += dhp[i] * wp[i];
    s += __shfl_xor(s, 1);
    s += __shfl_xor(s, 2);
    s += __shfl_xor(s, 4);
    if (part == 0) dec[(size_t)b * 1024 + e] = s;
}

// ---------------------------------------------------------------------------
// B (Wh) one-shot f32->bf16 into fragment-lane order. gid = ks*64 + nsub.
// ---------------------------------------------------------------------------
__global__ __launch_bounds__(256) void convert_frag_B(
    const float* __restrict__ src, unsigned short* __restrict__ out)
{
    int gid = blockIdx.x * 4 + (threadIdx.x >> 6);
    int lane = threadIdx.x & 63;
    int ms = gid & 63, ks = gid >> 6;
    const float* p = src + (size_t)(ms * 16 + (lane & 15)) * 1024
                         + ks * 32 + (lane >> 4) * 8;
    f32x4 a = *(const f32x4*)p;
    f32x4 b = *(const f32x4*)(p + 4);
    union { uint32_t d[4]; short8 v; } o;
    o.d[0] = pack_bf16(a.x, a.y); o.d[1] = pack_bf16(a.z, a.w);
    o.d[2] = pack_bf16(b.x, b.y); o.d[3] = pack_bf16(b.z, b.w);
    *(short8*)(out + (size_t)gid * 512 + lane * 8) = o.v;
}

// ---------------------------------------------------------------------------
// energy GEMM v8: A (x, f32) loaded direct from HBM, converted in-register,
// ds_written in fragment order LATE in the iteration (T14 issue-early/
// write-late); B pre-converted bf16 via global_load_lds. Double-buffered
// linear LDS (64 KB), ONE barrier per K-step:
//   { issue A-regs(ks+1), issue B-gload(ks+1) -> buf[c^1] ;
//     ds_read + 32 MFMA on buf[c] ;
//     pack+ds_write A(ks+1) -> buf[c^1] ;
//     s_waitcnt vmcnt(0) lgkmcnt(0) ; s_barrier }
// Hazards: buf[c^1]'s last readers finished at iter ks-1's barrier; pack
// forces A-load retirement; waitcnt makes B-LDS and A-writes visible.
// Tile 256x256, 8 waves (2x4, wave tile 128x64). Grid 1024, XCD-swizzled.
// ---------------------------------------------------------------------------
__global__ __launch_bounds__(512, 2) void energy_gemm_v8(
    const float* __restrict__ x,             // [65536,1024] f32
    const unsigned short* __restrict__ Bhi,  // [32 ks][64 nsub][512] bf16
    const float* __restrict__ dec, const float* __restrict__ v,
    float* __restrict__ energy)
{
    // 64 KB: two buffers of [A: 16 subtiles | B: 16 subtiles] x 1 KB
    __shared__ unsigned short lds[32768];

    int bid = blockIdx.x;
    int lid = (bid & 7) * 128 + (bid >> 3);  // 4 N-blocks of an M-block -> same XCD
    int mblk = lid >> 2, nblk = lid & 3;
    int m0 = mblk * BM, n0 = nblk * BN;
    int b = m0 >> 11;                        // 2048 rows per batch

    int t = threadIdx.x, wid = t >> 6, lane = t & 63;
    int wm = wid >> 2, wn = wid & 3;         // 2 x 4 waves, wave tile 128 x 64
    int kg = lane >> 4, lr = lane & 15;

    f32x4 acc[8][4] = {};

    // ---- A staging geometry: pass p handles subtile ms = p*8 + wid.
    // Wave covers 16 rows x 128 contiguous bytes (coalesced); LDS write is
    // one ds_write_b128 per thread, linear within the 1 KB subtile.
    int arow0 = m0 + (wid * 16) + (lane & 15);          // pass 0 row
    const float* apb0 = x + (size_t)arow0 * KDIM + (lane >> 4) * 8;
    const float* apb1 = apb0 + (size_t)128 * KDIM;      // pass 1 row (+8 subtiles)
    int wa0 = wid * 512 + lane * 8;
    int wa1 = wa0 + 8 * 512;

    // B staging: 16 chunks per K-tile, 2 per wave
    auto stageB = [&](int ksb, unsigned short* buf) {
        #pragma unroll
        for (int i = 0; i < 2; ++i) {
            int c = wid * 2 + i;
            gload_lds16(Bhi + ((size_t)ksb * 64 + nblk * 16 + c) * 512 + lane * 8,
                        &buf[8192 + c * 512]);
        }
    };

    f32x4 a0, a1, a2, a3;   // A(ks+1) in flight (16 f32 held one iteration)

    // ---- prologue: stage tile 0 into buf0
    stageB(0, &lds[0]);
    a0 = *(const f32x4*)apb0; a1 = *(const f32x4*)(apb0 + 4);
    a2 = *(const f32x4*)apb1; a3 = *(const f32x4*)(apb1 + 4);
    {
        union { uint32_t d[4]; short8 v; } o;
        o.d[0] = pack_bf16(a0.x, a0.y); o.d[1] = pack_bf16(a0.z, a0.w);
        o.d[2] = pack_bf16(a1.x, a1.y); o.d[3] = pack_bf16(a1.z, a1.w);
        *(short8*)&lds[wa0] = o.v;
        o.d[0] = pack_bf16(a2.x, a2.y); o.d[1] = pack_bf16(a2.z, a2.w);
        o.d[2] = pack_bf16(a3.x, a3.y); o.d[3] = pack_bf16(a3.z, a3.w);
        *(short8*)&lds[wa1] = o.v;
    }
    asm volatile("s_waitcnt vmcnt(0) lgkmcnt(0)" ::: "memory");
    __builtin_amdgcn_s_barrier();

    for (int ks = 0; ks < 32; ++ks) {
        unsigned short* bufA = &lds[(ks & 1) * 16384];
        unsigned short* bufB = bufA + 8192;
        unsigned short* nbuf = &lds[((ks + 1) & 1) * 16384];
        const bool st = (ks < 31);

        if (st) {
            // issue-early: A(ks+1) f32 loads + B(ks+1) gload_lds
            const float* p0 = apb0 + (ks + 1) * 32;
            const float* p1 = apb1 + (ks + 1) * 32;
            a0 = *(const f32x4*)p0; a1 = *(const f32x4*)(p0 + 4);
            a2 = *(const f32x4*)p1; a3 = *(const f32x4*)(p1 + 4);
            stageB(ks + 1, nbuf);
        }

        // ---- compute on buf[cur]: 12 ds_read_b128, 32 MFMA per wave
        short8 bf[4];
        #pragma unroll
        for (int ni = 0; ni < 4; ++ni)
            bf[ni] = *(const short8*)&bufB[(wn * 4 + ni) * 512 + lane * 8];
        #pragma unroll
        for (int mi = 0; mi < 8; ++mi) {
            short8 af = *(const short8*)&bufA[(wm * 8 + mi) * 512 + lane * 8];
            #pragma unroll
            for (int ni = 0; ni < 4; ++ni)
                acc[mi][ni] = __builtin_amdgcn_mfma_f32_16x16x32_bf16(af, bf[ni], acc[mi][ni], 0, 0, 0);
        }

        if (st) {
            // write-late: pack A(ks+1) and ds_write into the other buffer
            union { uint32_t d[4]; short8 v; } o;
            o.d[0] = pack_bf16(a0.x, a0.y); o.d[1] = pack_bf16(a0.z, a0.w);
            o.d[2] = pack_bf16(a1.x, a1.y); o.d[3] = pack_bf16(a1.z, a1.w);
            *(short8*)&nbuf[wa0] = o.v;
            o.d[0] = pack_bf16(a2.x, a2.y); o.d[1] = pack_bf16(a2.z, a2.w);
            o.d[2] = pack_bf16(a3.x, a3.y); o.d[3] = pack_bf16(a3.z, a3.w);
            *(short8*)&nbuf[wa1] = o.v;
        }

        // B(ks+1) landed + A-writes visible, then block-wide sync
        asm volatile("s_waitcnt vmcnt(0) lgkmcnt(0)" ::: "memory");
        __builtin_amdgcn_s_barrier();
    }

    // ---- epilogue: energy[m] += sum_n tanh(enc + dec) * v
    float vv[4], dd[4];
    #pragma unroll
    for (int ni = 0; ni < 4; ++ni) {
        int d = n0 + wn * 64 + ni * 16 + lr;
        vv[ni] = v[d];
        dd[ni] = dec[(size_t)b * 1024 + d];
    }
    #pragma unroll
    for (int mi = 0; mi < 8; ++mi) {
        #pragma unroll
        for (int r = 0; r < 4; ++r) {
            float local = 0.f;
            #pragma unroll
            for (int ni = 0; ni < 4; ++ni)
                local += fast_tanh(acc[mi][ni][r] + dd[ni]) * vv[ni];
            local += __shfl_xor(local, 1);
            local += __shfl_xor(local, 2);
            local += __shfl_xor(local, 4);
            local += __shfl_xor(local, 8);
            if (lr == 0) {
                int m = m0 + wm * 128 + mi * 16 + kg * 4 + r;
                atomicAdd(&energy[m], local);
            }
        }
    }
}

// ---------------------------------------------------------------------------
// Masked softmax over S per batch row. One block per b.
// ---------------------------------------------------------------------------
__global__ __launch_bounds__(256) void softmax_kernel(
    const float* __restrict__ energy, const int* __restrict__ mask,
    float* __restrict__ attn)
{
    int b = blockIdx.x;
    int t = threadIdx.x;
    int wid = t >> 6, lane = t & 63;
    __shared__ float wmax[4], wsum[4];

    float vals[8];
    float mx = -INFINITY;
    #pragma unroll
    for (int j = 0; j < 8; ++j) {
        int s = t + j * 256;
        float e = energy[(size_t)b * S_LEN + s];
        if (mask[(size_t)b * S_LEN + s] == 0) e = NEG_INF_F;
        vals[j] = e;
        mx = fmaxf(mx, e);
    }
    #pragma unroll
    for (int m = 1; m < 64; m <<= 1) mx = fmaxf(mx, __shfl_xor(mx, m));
    if (lane == 0) wmax[wid] = mx;
    __syncthreads();
    mx = fmaxf(fmaxf(wmax[0], wmax[1]), fmaxf(wmax[2], wmax[3]));

    float sum = 0.f;
    #pragma unroll
    for (int j = 0; j < 8; ++j) { vals[j] = expf(vals[j] - mx); sum += vals[j]; }
    #pragma unroll
    for (int m = 1; m < 64; m <<= 1) sum += __shfl_xor(sum, m);
    if (lane == 0) wsum[wid] = sum;
    __syncthreads();
    sum = wsum[0] + wsum[1] + wsum[2] + wsum[3];
    float inv = 1.f / sum;
    #pragma unroll
    for (int j = 0; j < 8; ++j)
        attn[(size_t)b * S_LEN + t + j * 256] = vals[j] * inv;
}

// ---------------------------------------------------------------------------
// context[b,e] = sum_s attn[b,s] * x[b,s,e]. Grid (4 e-chunks, 32 b, 16 s-chunks).
// ---------------------------------------------------------------------------
__global__ __launch_bounds__(256) void context_kernel(
    const float* __restrict__ attn, const float* __restrict__ x,
    float* __restrict__ ctx)
{
    int ec = blockIdx.x, b = blockIdx.y, sc = blockIdx.z;
    int e = ec * 256 + threadIdx.x;
    const float* xp = x + ((size_t)b * S_LEN + sc * 128) * KDIM + e;
    const float* ap = attn + (size_t)b * S_LEN + sc * 128;
    float acc = 0.f;
    #pragma unroll 4
    for (int s = 0; s < 128; ++s) acc += ap[s] * xp[(size_t)s * KDIM];
    atomicAdd(&ctx[(size_t)b * KDIM + e], acc);
}

// ---------------------------------------------------------------------------
extern "C" void kernel_launch(void* const* d_in, const int* in_sizes, int n_in,
                              void* d_out, int out_size, void* d_ws, size_t ws_size,
                              hipStream_t stream) {
    const float* dh   = (const float*)d_in[0];  // [32,1024]
    const float* x    = (const float*)d_in[1];  // [32,2048,1024]
    const int*   mask = (const int*)d_in[2];    // [32,2048]
    const float* Wh   = (const float*)d_in[3];  // [1024,1024]
    const float* Ws   = (const float*)d_in[4];  // [1024,1024]
    const float* v    = (const float*)d_in[5];  // [1024]

    float* ctx  = (float*)d_out;                 // [32*1024]
    float* attn = (float*)d_out + 32 * 1024;     // [32*2048]

    unsigned short* Bhi = (unsigned short*)d_ws;   // 1048576 el (2 MB)
    float* dec    = (float*)(Bhi + 1048576ull);    // 32768 f32
    float* energy = dec + 32768;                   // 65536 f32

    hipMemsetAsync(energy, 0, 65536 * sizeof(float), stream);
    hipMemsetAsync(ctx, 0, 32768 * sizeof(float), stream);

    dec_kernel<<<1024, 256, 0, stream>>>(dh, Ws, dec);
    convert_frag_B<<<512, 256, 0, stream>>>(Wh, Bhi);
    energy_gemm_v8<<<1024, 512, 0, stream>>>(x, Bhi, dec, v, energy);
    softmax_kernel<<<NBATCH, 256, 0, stream>>>(energy, mask, attn);
    context_kernel<<<dim3(4, NBATCH, 16), 256, 0, stream>>>(attn, x, ctx);
}

// Round 9
// 288.694 us; speedup vs baseline: 1.2394x; 1.2394x over previous
//
#include <hip/hip_runtime.h>
#include <stdint.h>
#include <math.h>

typedef __attribute__((ext_vector_type(8))) short short8;
typedef __attribute__((ext_vector_type(4))) float f32x4;

#define S_LEN 2048
#define NBATCH 32
#define KDIM 1024
#define NEG_INF_F (-1e9f)

#define BM 256
#define BN 256

// round-half-up f32 -> bf16, two at a time, packed into one dword
__device__ __forceinline__ uint32_t pack_bf16(float f0, float f1) {
    union { float f; uint32_t u; } a, b; a.f = f0; b.f = f1;
    return ((a.u + 0x8000u) >> 16) | ((b.u + 0x8000u) & 0xFFFF0000u);
}

__device__ __forceinline__ void gload_lds16(const unsigned short* g, unsigned short* l) {
    __builtin_amdgcn_global_load_lds(
        (const __attribute__((address_space(1))) void*)g,
        (__attribute__((address_space(3))) void*)l, 16, 0, 0);
}

// tanh(x) = 1 - 2/(exp(2x)+1); __expf -> v_exp_f32, rcp -> v_rcp_f32 (~1e-7)
__device__ __forceinline__ float fast_tanh(float x) {
    float e = __expf(2.0f * x);
    return 1.0f - 2.0f * __builtin_amdgcn_rcpf(e + 1.0f);
}

// ---------------------------------------------------------------------------
// dec[b,e] = sum_d dh[b,d] * Ws[e,d]   (one block per e)
// ---------------------------------------------------------------------------
__global__ __launch_bounds__(256) void dec_kernel(
    const float* __restrict__ dh, const float* __restrict__ Ws,
    float* __restrict__ dec)
{
    __shared__ float wrow[1024];
    int e = blockIdx.x;
    int t = threadIdx.x;
    #pragma unroll
    for (int i = t; i < 1024; i += 256) wrow[i] = Ws[(size_t)e * 1024 + i];
    __syncthreads();
    int b = t >> 3, part = t & 7;
    const float* dhp = dh + (size_t)b * 1024 + part * 128;
    const float* wp  = wrow + part * 128;
    float s = 0.f;
    #pragma unroll 8
    for (int i = 0; i < 128; ++i) s += dhp[i] * wp[i];
    s += __shfl_xor(s, 1);
    s += __shfl_xor(s, 2);
    s += __shfl_xor(s, 4);
    if (part == 0) dec[(size_t)b * 1024 + e] = s;
}

// ---------------------------------------------------------------------------
// B (Wh) one-shot f32->bf16 into fragment-lane order. gid = ks*64 + nsub.
// ---------------------------------------------------------------------------
__global__ __launch_bounds__(256) void convert_frag_B(
    const float* __restrict__ src, unsigned short* __restrict__ out)
{
    int gid = blockIdx.x * 4 + (threadIdx.x >> 6);
    int lane = threadIdx.x & 63;
    int ms = gid & 63, ks = gid >> 6;
    const float* p = src + (size_t)(ms * 16 + (lane & 15)) * 1024
                         + ks * 32 + (lane >> 4) * 8;
    f32x4 a = *(const f32x4*)p;
    f32x4 b = *(const f32x4*)(p + 4);
    union { uint32_t d[4]; short8 v; } o;
    o.d[0] = pack_bf16(a.x, a.y); o.d[1] = pack_bf16(a.z, a.w);
    o.d[2] = pack_bf16(b.x, b.y); o.d[3] = pack_bf16(b.z, b.w);
    *(short8*)(out + (size_t)gid * 512 + lane * 8) = o.v;
}

// ---------------------------------------------------------------------------
// A (x) one-shot f32->bf16 into fragment-lane order, ks-INNER gid mapping:
// the 32 consecutive waves sharing a 16-row group read it once (L2/L3-local).
// out[(ks*4096 + ms)*512 + lane*8 + j]
// ---------------------------------------------------------------------------
__global__ __launch_bounds__(256) void convert_frag_A(
    const float* __restrict__ src, unsigned short* __restrict__ out)
{
    int gid = blockIdx.x * 4 + (threadIdx.x >> 6);   // 0..131071
    int lane = threadIdx.x & 63;
    int ms = gid >> 5, ks = gid & 31;
    const float* p = src + (size_t)(ms * 16 + (lane & 15)) * 1024
                         + ks * 32 + (lane >> 4) * 8;
    f32x4 a = *(const f32x4*)p;
    f32x4 b = *(const f32x4*)(p + 4);
    union { uint32_t d[4]; short8 v; } o;
    o.d[0] = pack_bf16(a.x, a.y); o.d[1] = pack_bf16(a.z, a.w);
    o.d[2] = pack_bf16(b.x, b.y); o.d[3] = pack_bf16(b.z, b.w);
    *(short8*)(out + ((size_t)ks * 4096 + ms) * 512 + lane * 8) = o.v;
}

// ---------------------------------------------------------------------------
// energy GEMM v9: R6 structure with BK=64 — 16 K-steps, 64 MFMA/wave/step,
// one barrier+drain per step (amortizes the fixed stage/drain stall that
// dominated R6's 3320-cy step). Fragment-ordered bf16 operands, pure
// global_load_lds staging (8 chunks/wave/step), double-buffered 128 KB LDS.
// Per step: { issue 8 gloads for tile t+1 -> other buf ; for kslot 0,1:
//   12 ds_read_b128 + 32 MFMA ; } vmcnt(0) ; s_barrier.
// Tile 256x256, 8 waves (2x4, wave tile 128x64). Grid 1024, XCD-swizzled.
// ---------------------------------------------------------------------------
__global__ __launch_bounds__(512, 2) void energy_gemm_v9(
    const unsigned short* __restrict__ Ahi,  // [32 ks][4096 msub][512]
    const unsigned short* __restrict__ Bhi,  // [32 ks][64 nsub][512]
    const float* __restrict__ dec, const float* __restrict__ v,
    float* __restrict__ energy)
{
    // 128 KB: two buffers of [A: 32 subtiles | B: 32 subtiles] x 1 KB
    __shared__ unsigned short lds[65536];

    int bid = blockIdx.x;
    int lid = (bid & 7) * 128 + (bid >> 3);  // 4 N-blocks of an M-block -> same XCD
    int mblk = lid >> 2, nblk = lid & 3;
    int m0 = mblk * BM, n0 = nblk * BN;
    int b = m0 >> 11;                        // 2048 rows per batch

    int t = threadIdx.x, wid = t >> 6, lane = t & 63;
    int wm = wid >> 2, wn = wid & 3;         // 2 x 4 waves, wave tile 128 x 64
    int kg = lane >> 4, lr = lane & 15;

    f32x4 acc[8][4] = {};

    // stage one 64-wide K-tile (t2 = 0..15): 64 chunks, 8 per wave.
    // chunk c (wave handles ca=wid*4+i for A and same for B):
    //   A: ks = 2*t2 + (c>>4), msub = mblk*16 + (c&15), dest bufA + c*512
    //   B: ks = 2*t2 + (c>>4), nsub = nblk*16 + (c&15), dest bufB + c*512
    auto stage = [&](int t2, unsigned short* buf) {
        #pragma unroll
        for (int i = 0; i < 4; ++i) {
            int c = wid * 4 + i;
            int ks = 2 * t2 + (c >> 4);
            gload_lds16(Ahi + ((size_t)ks * 4096 + mblk * 16 + (c & 15)) * 512 + lane * 8,
                        &buf[c * 512]);
        }
        #pragma unroll
        for (int i = 0; i < 4; ++i) {
            int c = wid * 4 + i;
            int ks = 2 * t2 + (c >> 4);
            gload_lds16(Bhi + ((size_t)ks * 64 + nblk * 16 + (c & 15)) * 512 + lane * 8,
                        &buf[16384 + c * 512]);
        }
    };

    // ---- prologue: stage tile 0 into buf0
    stage(0, &lds[0]);
    asm volatile("s_waitcnt vmcnt(0)" ::: "memory");
    __builtin_amdgcn_s_barrier();

    for (int ts = 0; ts < 16; ++ts) {
        unsigned short* bufA = &lds[(ts & 1) * 32768];
        unsigned short* bufB = bufA + 16384;

        if (ts < 15) stage(ts + 1, &lds[((ts + 1) & 1) * 32768]);

        // ---- compute on buf[cur]: 2 kslots x (12 ds_read_b128 + 32 MFMA)
        #pragma unroll
        for (int ksl = 0; ksl < 2; ++ksl) {
            short8 bf[4];
            #pragma unroll
            for (int ni = 0; ni < 4; ++ni)
                bf[ni] = *(const short8*)&bufB[(ksl * 16 + wn * 4 + ni) * 512 + lane * 8];
            #pragma unroll
            for (int mi = 0; mi < 8; ++mi) {
                short8 af = *(const short8*)&bufA[(ksl * 16 + wm * 8 + mi) * 512 + lane * 8];
                #pragma unroll
                for (int ni = 0; ni < 4; ++ni)
                    acc[mi][ni] = __builtin_amdgcn_mfma_f32_16x16x32_bf16(af, bf[ni], acc[mi][ni], 0, 0, 0);
            }
        }

        // next-tile loads (issued ~64 MFMA ago) retire; then block-wide sync
        asm volatile("s_waitcnt vmcnt(0)" ::: "memory");
        __builtin_amdgcn_s_barrier();
    }

    // ---- epilogue: energy[m] += sum_n tanh(enc + dec) * v
    float vv[4], dd[4];
    #pragma unroll
    for (int ni = 0; ni < 4; ++ni) {
        int d = n0 + wn * 64 + ni * 16 + lr;
        vv[ni] = v[d];
        dd[ni] = dec[(size_t)b * 1024 + d];
    }
    #pragma unroll
    for (int mi = 0; mi < 8; ++mi) {
        #pragma unroll
        for (int r = 0; r < 4; ++r) {
            float local = 0.f;
            #pragma unroll
            for (int ni = 0; ni < 4; ++ni)
                local += fast_tanh(acc[mi][ni][r] + dd[ni]) * vv[ni];
            local += __shfl_xor(local, 1);
            local += __shfl_xor(local, 2);
            local += __shfl_xor(local, 4);
            local += __shfl_xor(local, 8);
            if (lr == 0) {
                int m = m0 + wm * 128 + mi * 16 + kg * 4 + r;
                atomicAdd(&energy[m], local);
            }
        }
    }
}

// ---------------------------------------------------------------------------
// Masked softmax over S per batch row. One block per b.
// ---------------------------------------------------------------------------
__global__ __launch_bounds__(256) void softmax_kernel(
    const float* __restrict__ energy, const int* __restrict__ mask,
    float* __restrict__ attn)
{
    int b = blockIdx.x;
    int t = threadIdx.x;
    int wid = t >> 6, lane = t & 63;
    __shared__ float wmax[4], wsum[4];

    float vals[8];
    float mx = -INFINITY;
    #pragma unroll
    for (int j = 0; j < 8; ++j) {
        int s = t + j * 256;
        float e = energy[(size_t)b * S_LEN + s];
        if (mask[(size_t)b * S_LEN + s] == 0) e = NEG_INF_F;
        vals[j] = e;
        mx = fmaxf(mx, e);
    }
    #pragma unroll
    for (int m = 1; m < 64; m <<= 1) mx = fmaxf(mx, __shfl_xor(mx, m));
    if (lane == 0) wmax[wid] = mx;
    __syncthreads();
    mx = fmaxf(fmaxf(wmax[0], wmax[1]), fmaxf(wmax[2], wmax[3]));

    float sum = 0.f;
    #pragma unroll
    for (int j = 0; j < 8; ++j) { vals[j] = expf(vals[j] - mx); sum += vals[j]; }
    #pragma unroll
    for (int m = 1; m < 64; m <<= 1) sum += __shfl_xor(sum, m);
    if (lane == 0) wsum[wid] = sum;
    __syncthreads();
    sum = wsum[0] + wsum[1] + wsum[2] + wsum[3];
    float inv = 1.f / sum;
    #pragma unroll
    for (int j = 0; j < 8; ++j)
        attn[(size_t)b * S_LEN + t + j * 256] = vals[j] * inv;
}

// ---------------------------------------------------------------------------
// context[b,e] = sum_s attn[b,s] * x[b,s,e]. Grid (4 e-chunks, 32 b, 16 s-chunks).
// ---------------------------------------------------------------------------
__global__ __launch_bounds__(256) void context_kernel(
    const float* __restrict__ attn, const float* __restrict__ x,
    float* __restrict__ ctx)
{
    int ec = blockIdx.x, b = blockIdx.y, sc = blockIdx.z;
    int e = ec * 256 + threadIdx.x;
    const float* xp = x + ((size_t)b * S_LEN + sc * 128) * KDIM + e;
    const float* ap = attn + (size_t)b * S_LEN + sc * 128;
    float acc = 0.f;
    #pragma unroll 4
    for (int s = 0; s < 128; ++s) acc += ap[s] * xp[(size_t)s * KDIM];
    atomicAdd(&ctx[(size_t)b * KDIM + e], acc);
}

// ---------------------------------------------------------------------------
extern "C" void kernel_launch(void* const* d_in, const int* in_sizes, int n_in,
                              void* d_out, int out_size, void* d_ws, size_t ws_size,
                              hipStream_t stream) {
    const float* dh   = (const float*)d_in[0];  // [32,1024]
    const float* x    = (const float*)d_in[1];  // [32,2048,1024]
    const int*   mask = (const int*)d_in[2];    // [32,2048]
    const float* Wh   = (const float*)d_in[3];  // [1024,1024]
    const float* Ws   = (const float*)d_in[4];  // [1024,1024]
    const float* v    = (const float*)d_in[5];  // [1024]

    float* ctx  = (float*)d_out;                 // [32*1024]
    float* attn = (float*)d_out + 32 * 1024;     // [32*2048]

    unsigned short* Ahi = (unsigned short*)d_ws;   // 67108864 el (128 MB)
    unsigned short* Bhi = Ahi + 67108864ull;       // 1048576 el (2 MB)
    float* dec    = (float*)(Bhi + 1048576ull);    // 32768 f32
    float* energy = dec + 32768;                   // 65536 f32

    hipMemsetAsync(energy, 0, 65536 * sizeof(float), stream);
    hipMemsetAsync(ctx, 0, 32768 * sizeof(float), stream);

    dec_kernel<<<1024, 256, 0, stream>>>(dh, Ws, dec);
    convert_frag_B<<<512, 256, 0, stream>>>(Wh, Bhi);
    convert_frag_A<<<32768, 256, 0, stream>>>(x, Ahi);
    energy_gemm_v9<<<1024, 512, 0, stream>>>(Ahi, Bhi, dec, v, energy);
    softmax_kernel<<<NBATCH, 256, 0, stream>>>(energy, mask, attn);
    context_kernel<<<dim3(4, NBATCH, 16), 256, 0, stream>>>(attn, x, ctx);
}

// Round 11
// 261.168 us; speedup vs baseline: 1.3701x; 1.1054x over previous
//
#include <hip/hip_runtime.h>
#include <stdint.h>
#include <math.h>

typedef __attribute__((ext_vector_type(8))) short short8;
typedef __attribute__((ext_vector_type(4))) float f32x4;

#define S_LEN 2048
#define NBATCH 32
#define KDIM 1024
#define NEG_INF_F (-1e9f)

#define BM 256
#define BN 256
#define LDA 72   /* A LDS row stride in ushorts: 64 + 8 pad -> 2-way (free) on frag reads */

// round-half-up f32 -> bf16, two at a time, packed into one dword
__device__ __forceinline__ uint32_t pack_bf16(float f0, float f1) {
    union { float f; uint32_t u; } a, b; a.f = f0; b.f = f1;
    return ((a.u + 0x8000u) >> 16) | ((b.u + 0x8000u) & 0xFFFF0000u);
}

__device__ __forceinline__ void gload_lds16(const unsigned short* g, unsigned short* l) {
    __builtin_amdgcn_global_load_lds(
        (const __attribute__((address_space(1))) void*)g,
        (__attribute__((address_space(3))) void*)l, 16, 0, 0);
}

// tanh(x) = 1 - 2/(exp(2x)+1); __expf -> v_exp_f32, rcp -> v_rcp_f32 (~1e-7)
__device__ __forceinline__ float fast_tanh(float x) {
    float e = __expf(2.0f * x);
    return 1.0f - 2.0f * __builtin_amdgcn_rcpf(e + 1.0f);
}

// ---------------------------------------------------------------------------
// dec[b,e] = sum_d dh[b,d] * Ws[e,d]   (one block per e)
// ---------------------------------------------------------------------------
__global__ __launch_bounds__(256) void dec_kernel(
    const float* __restrict__ dh, const float* __restrict__ Ws,
    float* __restrict__ dec)
{
    __shared__ float wrow[1024];
    int e = blockIdx.x;
    int t = threadIdx.x;
    #pragma unroll
    for (int i = t; i < 1024; i += 256) wrow[i] = Ws[(size_t)e * 1024 + i];
    __syncthreads();
    int b = t >> 3, part = t & 7;
    const float* dhp = dh + (size_t)b * 1024 + part * 128;
    const float* wp  = wrow + part * 128;
    float s = 0.f;
    #pragma unroll 8
    for (int i = 0; i < 128; ++i) s += dhp[i] * wp[i];
    s += __shfl_xor(s, 1);
    s += __shfl_xor(s, 2);
    s += __shfl_xor(s, 4);
    if (part == 0) dec[(size_t)b * 1024 + e] = s;
}

// ---------------------------------------------------------------------------
// B (Wh) one-shot f32->bf16 into fragment-lane order. gid = ks*64 + nsub.
// ---------------------------------------------------------------------------
__global__ __launch_bounds__(256) void convert_frag_B(
    const float* __restrict__ src, unsigned short* __restrict__ out)
{
    int gid = blockIdx.x * 4 + (threadIdx.x >> 6);
    int lane = threadIdx.x & 63;
    int ms = gid & 63, ks = gid >> 6;
    const float* p = src + (size_t)(ms * 16 + (lane & 15)) * 1024
                         + ks * 32 + (lane >> 4) * 8;
    f32x4 a = *(const f32x4*)p;
    f32x4 b = *(const f32x4*)(p + 4);
    union { uint32_t d[4]; short8 v; } o;
    o.d[0] = pack_bf16(a.x, a.y); o.d[1] = pack_bf16(a.z, a.w);
    o.d[2] = pack_bf16(b.x, b.y); o.d[3] = pack_bf16(b.z, b.w);
    *(short8*)(out + (size_t)gid * 512 + lane * 8) = o.v;
}

// ---------------------------------------------------------------------------
// energy GEMM v10: A (x, f32) fused-converted — coalesced row-major loads,
// in-reg pack, ds_write into row-major padded A-tile (stride LDA=72 ush:
// frag ds_read_b128 = 2-way aliasing = free; writes tile banks evenly).
// B pre-converted bf16 fragment-order via global_load_lds. BK=64, 16 steps,
// double-buffered LDS (136 KB). A staged in 2 batches of 16 f32 aligned with
// the 2 kslots (peak +16 VGPR, fits 2 waves/SIMD at 256 unified regs).
// Per step: { issue B gloads + A batch0 ; kslot0: 12 ds_read + 32 MFMA ;
//   write b0 ; sched_barrier ; issue A batch1 ; kslot1 ; write b1 ;
//   vmcnt(0) lgkm(0) ; s_barrier }
// Tile 256x256, 8 waves (2x4, wave tile 128x64). Grid 1024, XCD-swizzled.
// ---------------------------------------------------------------------------
__global__ __launch_bounds__(512, 2) void energy_gemm_v10(
    const float* __restrict__ x,             // [65536,1024] f32
    const unsigned short* __restrict__ Bhi,  // [32 ks][64 nsub][512] bf16
    const float* __restrict__ dec, const float* __restrict__ v,
    float* __restrict__ energy)
{
    // per buffer: A row-major [256][LDA] = 18432 ush | B frag 32x512 = 16384 ush
    __shared__ unsigned short lds[69632];    // 2 x 34816 ush = 136 KB

    int bid = blockIdx.x;
    int lid = (bid & 7) * 128 + (bid >> 3);  // 4 N-blocks of an M-block -> same XCD
    int mblk = lid >> 2, nblk = lid & 3;
    int m0 = mblk * BM, n0 = nblk * BN;
    int b = m0 >> 11;                        // 2048 rows per batch

    int t = threadIdx.x, wid = t >> 6, lane = t & 63;
    int wm = wid >> 2, wn = wid & 3;         // 2 x 4 waves, wave tile 128 x 64
    int kg = lane >> 4, lr = lane & 15;

    f32x4 acc[8][4] = {};

    // A staging geometry: thread t covers row = t>>1, 16 consecutive cols at
    // cg*16 within a 32-col batch. 2 threads = 128 contiguous bytes (coalesced).
    int arow = t >> 1, acg = t & 1;
    const float* aptr = x + (size_t)(m0 + arow) * KDIM + acg * 16;
    int awoff = arow * LDA + acg * 16;       // ush offset within A tile

    // A-staging registers (single declaration; macros assign)
    f32x4 A0, A1, A2, A3;

    // B staging: 32 chunks per K-tile(64), 4 per wave
    auto stageB = [&](int t2, unsigned short* bufB) {
        #pragma unroll
        for (int i = 0; i < 4; ++i) {
            int c = wid * 4 + i;
            int ks = 2 * t2 + (c >> 4);
            gload_lds16(Bhi + ((size_t)ks * 64 + nblk * 16 + (c & 15)) * 512 + lane * 8,
                        &bufB[c * 512]);
        }
    };

#define A_LOAD(t2, bb) { \
    const float* ap_ = aptr + (t2) * 64 + (bb) * 32; \
    A0 = *(const f32x4*)ap_;        A1 = *(const f32x4*)(ap_ + 4); \
    A2 = *(const f32x4*)(ap_ + 8);  A3 = *(const f32x4*)(ap_ + 12); }
#define A_WRITE(bufA, bb) { \
    union { uint32_t d[8]; } o_; \
    o_.d[0] = pack_bf16(A0.x, A0.y); o_.d[1] = pack_bf16(A0.z, A0.w); \
    o_.d[2] = pack_bf16(A1.x, A1.y); o_.d[3] = pack_bf16(A1.z, A1.w); \
    o_.d[4] = pack_bf16(A2.x, A2.y); o_.d[5] = pack_bf16(A2.z, A2.w); \
    o_.d[6] = pack_bf16(A3.x, A3.y); o_.d[7] = pack_bf16(A3.z, A3.w); \
    *(short8*)&(bufA)[awoff + (bb) * 32]     = *(short8*)&o_.d[0]; \
    *(short8*)&(bufA)[awoff + (bb) * 32 + 8] = *(short8*)&o_.d[4]; }

    // kslot compute: 4 B-frag reads + 8 A-frag reads + 32 MFMA
#define KSLOT(bufA, bufB, ksl) { \
    short8 bf[4]; \
    _Pragma("unroll") \
    for (int ni = 0; ni < 4; ++ni) \
        bf[ni] = *(const short8*)&(bufB)[((ksl) * 16 + wn * 4 + ni) * 512 + lane * 8]; \
    _Pragma("unroll") \
    for (int mi = 0; mi < 8; ++mi) { \
        short8 af = *(const short8*)&(bufA)[(wm * 128 + mi * 16 + lr) * LDA + (ksl) * 32 + kg * 8]; \
        _Pragma("unroll") \
        for (int ni = 0; ni < 4; ++ni) \
            acc[mi][ni] = __builtin_amdgcn_mfma_f32_16x16x32_bf16(af, bf[ni], acc[mi][ni], 0, 0, 0); \
    } }

    // ---- prologue: stage tile 0 into buf0 (A both batches + B)
    {
        unsigned short* bufA = &lds[0];
        stageB(0, &lds[18432]);
        A_LOAD(0, 0); A_WRITE(bufA, 0);
        A_LOAD(0, 1); A_WRITE(bufA, 1);
    }
    asm volatile("s_waitcnt vmcnt(0) lgkmcnt(0)" ::: "memory");
    __builtin_amdgcn_s_barrier();

    for (int ts = 0; ts < 16; ++ts) {
        unsigned short* bufA = &lds[(ts & 1) * 34816];
        unsigned short* bufB = bufA + 18432;
        unsigned short* nbufA = &lds[((ts + 1) & 1) * 34816];
        unsigned short* nbufB = nbufA + 18432;
        const bool st = (ts < 15);

        if (st) {
            stageB(ts + 1, nbufB);
            A_LOAD(ts + 1, 0);                 // batch0 in flight (16 f32)
            KSLOT(bufA, bufB, 0);
            A_WRITE(nbufA, 0);                 // retires batch0 loads
            __builtin_amdgcn_sched_barrier(0); // pin batch1 below
            A_LOAD(ts + 1, 1);                 // batch1 in flight under kslot1
            KSLOT(bufA, bufB, 1);
            A_WRITE(nbufA, 1);
        } else {
            KSLOT(bufA, bufB, 0);
            KSLOT(bufA, bufB, 1);
        }

        asm volatile("s_waitcnt vmcnt(0) lgkmcnt(0)" ::: "memory");
        __builtin_amdgcn_s_barrier();
    }

    // ---- epilogue: energy[m] += sum_n tanh(enc + dec) * v
    float vv[4], dd[4];
    #pragma unroll
    for (int ni = 0; ni < 4; ++ni) {
        int d = n0 + wn * 64 + ni * 16 + lr;
        vv[ni] = v[d];
        dd[ni] = dec[(size_t)b * 1024 + d];
    }
    #pragma unroll
    for (int mi = 0; mi < 8; ++mi) {
        #pragma unroll
        for (int r = 0; r < 4; ++r) {
            float local = 0.f;
            #pragma unroll
            for (int ni = 0; ni < 4; ++ni)
                local += fast_tanh(acc[mi][ni][r] + dd[ni]) * vv[ni];
            local += __shfl_xor(local, 1);
            local += __shfl_xor(local, 2);
            local += __shfl_xor(local, 4);
            local += __shfl_xor(local, 8);
            if (lr == 0) {
                int m = m0 + wm * 128 + mi * 16 + kg * 4 + r;
                atomicAdd(&energy[m], local);
            }
        }
    }
}

// ---------------------------------------------------------------------------
// Masked softmax over S per batch row. One block per b.
// ---------------------------------------------------------------------------
__global__ __launch_bounds__(256) void softmax_kernel(
    const float* __restrict__ energy, const int* __restrict__ mask,
    float* __restrict__ attn)
{
    int b = blockIdx.x;
    int t = threadIdx.x;
    int wid = t >> 6, lane = t & 63;
    __shared__ float wmax[4], wsum[4];

    float vals[8];
    float mx = -INFINITY;
    #pragma unroll
    for (int j = 0; j < 8; ++j) {
        int s = t + j * 256;
        float e = energy[(size_t)b * S_LEN + s];
        if (mask[(size_t)b * S_LEN + s] == 0) e = NEG_INF_F;
        vals[j] = e;
        mx = fmaxf(mx, e);
    }
    #pragma unroll
    for (int m = 1; m < 64; m <<= 1) mx = fmaxf(mx, __shfl_xor(mx, m));
    if (lane == 0) wmax[wid] = mx;
    __syncthreads();
    mx = fmaxf(fmaxf(wmax[0], wmax[1]), fmaxf(wmax[2], wmax[3]));

    float sum = 0.f;
    #pragma unroll
    for (int j = 0; j < 8; ++j) { vals[j] = expf(vals[j] - mx); sum += vals[j]; }
    #pragma unroll
    for (int m = 1; m < 64; m <<= 1) sum += __shfl_xor(sum, m);
    if (lane == 0) wsum[wid] = sum;
    __syncthreads();
    sum = wsum[0] + wsum[1] + wsum[2] + wsum[3];
    float inv = 1.f / sum;
    #pragma unroll
    for (int j = 0; j < 8; ++j)
        attn[(size_t)b * S_LEN + t + j * 256] = vals[j] * inv;
}

// ---------------------------------------------------------------------------
// context[b,e] = sum_s attn[b,s] * x[b,s,e]. Grid (4 e-chunks, 32 b, 16 s-chunks).
// ---------------------------------------------------------------------------
__global__ __launch_bounds__(256) void context_kernel(
    const float* __restrict__ attn, const float* __restrict__ x,
    float* __restrict__ ctx)
{
    int ec = blockIdx.x, b = blockIdx.y, sc = blockIdx.z;
    int e = ec * 256 + threadIdx.x;
    const float* xp = x + ((size_t)b * S_LEN + sc * 128) * KDIM + e;
    const float* ap = attn + (size_t)b * S_LEN + sc * 128;
    float acc = 0.f;
    #pragma unroll 4
    for (int s = 0; s < 128; ++s) acc += ap[s] * xp[(size_t)s * KDIM];
    atomicAdd(&ctx[(size_t)b * KDIM + e], acc);
}

// ---------------------------------------------------------------------------
extern "C" void kernel_launch(void* const* d_in, const int* in_sizes, int n_in,
                              void* d_out, int out_size, void* d_ws, size_t ws_size,
                              hipStream_t stream) {
    const float* dh   = (const float*)d_in[0];  // [32,1024]
    const float* x    = (const float*)d_in[1];  // [32,2048,1024]
    const int*   mask = (const int*)d_in[2];    // [32,2048]
    const float* Wh   = (const float*)d_in[3];  // [1024,1024]
    const float* Ws   = (const float*)d_in[4];  // [1024,1024]
    const float* v    = (const float*)d_in[5];  // [1024]

    float* ctx  = (float*)d_out;                 // [32*1024]
    float* attn = (float*)d_out + 32 * 1024;     // [32*2048]

    unsigned short* Bhi = (unsigned short*)d_ws;   // 1048576 el (2 MB)
    float* dec    = (float*)(Bhi + 1048576ull);    // 32768 f32
    float* energy = dec + 32768;                   // 65536 f32

    hipMemsetAsync(energy, 0, 65536 * sizeof(float), stream);
    hipMemsetAsync(ctx, 0, 32768 * sizeof(float), stream);

    dec_kernel<<<1024, 256, 0, stream>>>(dh, Ws, dec);
    convert_frag_B<<<512, 256, 0, stream>>>(Wh, Bhi);
    energy_gemm_v10<<<1024, 512, 0, stream>>>(x, Bhi, dec, v, energy);
    softmax_kernel<<<NBATCH, 256, 0, stream>>>(energy, mask, attn);
    context_kernel<<<dim3(4, NBATCH, 16), 256, 0, stream>>>(attn, x, ctx);
}